// Round 15
// baseline (224.777 us; speedup 1.0000x reference)
//
#include <hip/hip_runtime.h>
#include <hip/hip_bf16.h>

#define DIN 512
#define HID 512

#define AS1 __attribute__((address_space(1)))
#define AS3 __attribute__((address_space(3)))

typedef __attribute__((ext_vector_type(8))) short bfrag;     // 8 bf16 (4 VGPRs)
typedef __attribute__((ext_vector_type(4))) float ffrag;     // 4 fp32 acc
typedef __attribute__((ext_vector_type(8))) unsigned short u16x8;
typedef __attribute__((ext_vector_type(4))) unsigned short u16x4;

// Ledger: R13 best = 210.86.  Wins: R10 XOR-rotation decode (-0.7), R11
// scan-delete (-0.8), R12 TA-dedup csr2 (-7.0), R13 8-record dedup (-3.0).
// Failed & reverted: R5 NT (+28), R6 batch-8 (+8.5), R7 global sort (+151),
// R8 local sort (+8), R9 csr2 pipeline (+6.4).
// R14 (resubmit; prior run was an infra failure, R1 precedent): delete the
// xb intermediate.  GEMM-1 stages A directly from f32 x, converting to bf16
// in-register before the LDS write (reg-staged A-path; B-path keeps
// global_load_lds).  x-traffic 102.6 MB -> 51.4 MB (~-8us); prelude drops
// its x-conversion blocks.  Same __float2bfloat16 RNE -> bitwise-identical
// hw.  Rows >= N clamp to N-1 (in-bounds; hw pad rows never read —
// agg_relu zero-fills h1's pad).

// ---------------------------------------------------------------------------
// Prelude: transpose+cvt both weights, count edges.  (x-conversion removed.)
// ---------------------------------------------------------------------------
__global__ __launch_bounds__(256) void prelude(const float* __restrict__ W1,
                                               const float* __restrict__ W2,
                                               unsigned short* __restrict__ Wt1,
                                               unsigned short* __restrict__ Wt2,
                                               const int* __restrict__ dst,
                                               int* __restrict__ cnt,
                                               int E) {
    int b = blockIdx.x;
    if (b < 512) {
        int which = b >> 8;
        int bb = b & 255;
        const float* W = which ? W2 : W1;
        unsigned short* Wt = which ? Wt2 : Wt1;
        __shared__ float t[32][33];
        int tid = threadIdx.x;
        int tx = tid & 31, ty = tid >> 5;          // 32 x 8
        int n0 = (bb & 15) * 32, k0 = (bb >> 4) * 32;
#pragma unroll
        for (int s = 0; s < 4; ++s)
            t[ty + 8 * s][tx] = W[(size_t)(k0 + ty + 8 * s) * 512 + n0 + tx];
        __syncthreads();
#pragma unroll
        for (int s = 0; s < 4; ++s) {
            __hip_bfloat16 v = __float2bfloat16(t[tx][ty + 8 * s]);
            Wt[(size_t)(n0 + ty + 8 * s) * 512 + k0 + tx] = *(unsigned short*)&v;
        }
    } else {
        int e = (b - 512) * 256 + threadIdx.x;
        if (e < E) atomicAdd(&cnt[dst[e]], 1);
    }
}

// ---------------------------------------------------------------------------
// XCD-swizzled tile mapping for the 128x256 GEMM.
// ---------------------------------------------------------------------------
__device__ inline bool tile_map2(int b, int Mtiles, int& m0, int& n0) {
    int xcd = b & 7, i = b >> 3;
    int nt = i & 1, mg = i >> 1;
    int mt = mg * 8 + xcd;
    if (mt >= Mtiles) return false;
    m0 = mt * 128;
    n0 = nt * 256;
    return true;
}

// Shared GEMM body: 128x256 tile, BK=64, XOR-swizzled LDS, operand-swapped
// mfma -> packed 8-B epilogue stores.  ROTA: A operand uses the XOR-rotated
// layout (h1).  F32A: A staged from f32 source with in-register bf16 cvt
// (reg-staged ds_write; LDS layout/swizzle identical to the gload_lds path).
// C store is always XOR-rotated: physical group = logical group ^ (row & 7).
template <bool ROTA, bool F32A>
__device__ __forceinline__ void gemm_body(const short* __restrict__ A,
                                          const float* __restrict__ Xf,
                                          unsigned short* __restrict__ C,
                                          const short* __restrict__ B,
                                          int Mtiles, int Nclamp, int bidx,
                                          short* As, short* Bs) {
    const int K = 512;
    int m0, n0;
    if (!tile_map2(bidx, Mtiles, m0, n0)) return;
    int tid = threadIdx.x;
    int lane = tid & 63, wave = tid >> 6;
    int wm = (wave & 1) * 64;         // 2x2 waves: 64 m x 128 n each
    int wn = (wave >> 1) * 128;
    int r = lane & 15, q = lane >> 4;

    unsigned aoff[4]; int aldso[4]; int arow_[4]; int awr[4];
#pragma unroll
    for (int i = 0; i < 4; ++i) {
        int s = i * 256 + tid;
        int row = s >> 3;
        int c = (s & 7) ^ (row & 7);
        arow_[i] = m0 + row;
        if (F32A) {
            int crow = (m0 + row < Nclamp) ? (m0 + row) : (Nclamp - 1);
            aoff[i] = (unsigned)crow * K + c * 8;          // f32 element offset
        } else {
            aoff[i] = (unsigned)(m0 + row) * K + c * 8;    // bf16 element offset
        }
        aldso[i] = (i * 256 + (tid & ~63)) * 8;            // gload_lds base (shorts)
        awr[i] = (i * 256 + tid) * 8;                      // reg-staged write addr
    }
    unsigned boff[8]; int bldso[8];
#pragma unroll
    for (int i = 0; i < 8; ++i) {
        int s = i * 256 + tid;
        int row = s >> 3;
        int c = (s & 7) ^ (row & 7);
        boff[i] = (unsigned)(n0 + row) * K + c * 8;
        bldso[i] = (i * 256 + (tid & ~63)) * 8;
    }

    ffrag acc[4][8];
#pragma unroll
    for (int i = 0; i < 4; ++i)
#pragma unroll
        for (int j = 0; j < 8; ++j) acc[i][j] = ffrag{0.f, 0.f, 0.f, 0.f};

    for (int k0 = 0; k0 < K; k0 += 64) {
        if (F32A) {
            // issue f32 loads first (long latency), B gload_lds overlaps cvt
            float4 lo[4], hi[4];
#pragma unroll
            for (int i = 0; i < 4; ++i) {
                lo[i] = *(const float4*)&Xf[aoff[i] + k0];
                hi[i] = *(const float4*)&Xf[aoff[i] + k0 + 4];
            }
#pragma unroll
            for (int i = 0; i < 8; ++i)
                __builtin_amdgcn_global_load_lds((const AS1 void*)(B + boff[i] + k0),
                                                 (AS3 void*)(Bs + bldso[i]), 16, 0, 0);
#pragma unroll
            for (int i = 0; i < 4; ++i) {
                unsigned short o[8];
                __hip_bfloat16 t;
                t = __float2bfloat16(lo[i].x); o[0] = *(unsigned short*)&t;
                t = __float2bfloat16(lo[i].y); o[1] = *(unsigned short*)&t;
                t = __float2bfloat16(lo[i].z); o[2] = *(unsigned short*)&t;
                t = __float2bfloat16(lo[i].w); o[3] = *(unsigned short*)&t;
                t = __float2bfloat16(hi[i].x); o[4] = *(unsigned short*)&t;
                t = __float2bfloat16(hi[i].y); o[5] = *(unsigned short*)&t;
                t = __float2bfloat16(hi[i].z); o[6] = *(unsigned short*)&t;
                t = __float2bfloat16(hi[i].w); o[7] = *(unsigned short*)&t;
                *(u16x8*)&As[awr[i]] = *(u16x8*)o;
            }
        } else {
#pragma unroll
            for (int i = 0; i < 4; ++i) {
                unsigned ka;
                if (ROTA) ka = ((unsigned)((k0 >> 6) ^ (arow_[i] & 7))) << 6;  // XOR-rotated window
                else ka = (unsigned)k0;
                __builtin_amdgcn_global_load_lds((const AS1 void*)(A + aoff[i] + ka),
                                                 (AS3 void*)(As + aldso[i]), 16, 0, 0);
            }
#pragma unroll
            for (int i = 0; i < 8; ++i)
                __builtin_amdgcn_global_load_lds((const AS1 void*)(B + boff[i] + k0),
                                                 (AS3 void*)(Bs + bldso[i]), 16, 0, 0);
        }
        __syncthreads();

#pragma unroll
        for (int s2 = 0; s2 < 2; ++s2) {
            bfrag af[4], bfr[8];
#pragma unroll
            for (int i = 0; i < 4; ++i) {
                int arow = wm + i * 16 + r;
                int ach = (s2 * 4 + q) ^ (arow & 7);
                af[i] = *(const bfrag*)&As[arow * 64 + ach * 8];
            }
#pragma unroll
            for (int j = 0; j < 8; ++j) {
                int brow = wn + j * 16 + r;
                int bch = (s2 * 4 + q) ^ (brow & 7);
                bfr[j] = *(const bfrag*)&Bs[brow * 64 + bch * 8];
            }
#pragma unroll
            for (int i = 0; i < 4; ++i)
#pragma unroll
                for (int j = 0; j < 8; ++j)
                    acc[i][j] = __builtin_amdgcn_mfma_f32_16x16x32_bf16(bfr[j], af[i], acc[i][j], 0, 0, 0);
        }
        __syncthreads();
    }

#pragma unroll
    for (int i = 0; i < 4; ++i) {
        int m = m0 + wm + i * 16 + r;
#pragma unroll
        for (int j = 0; j < 8; ++j) {
            int n = n0 + wn + j * 16 + q * 4;                     // logical col
            int np = (((n >> 6) ^ (m & 7)) << 6) | (n & 63);      // XOR-rotated col
            u16x4 o;
#pragma unroll
            for (int reg = 0; reg < 4; ++reg) {
                __hip_bfloat16 v = __float2bfloat16(acc[i][j][reg]);
                o[reg] = *(unsigned short*)&v;
            }
            *(u16x4*)&C[(size_t)m * 512 + np] = o;
        }
    }
}

// Layer-1 fused launch: blocks [0,G) run the GEMM (A staged from f32 x);
// blocks [G,G+EJ) scatter edge records into FIXED-STRIDE csr2.
// rec.x = s<<10 | (s&7)<<7 (pre-rotated); rec.y = rsqrtf(cnt[s]+1)*rsqrtf(cnt[d]+1).
__global__ __launch_bounds__(256, 2) void gemm_fill(const float* __restrict__ Xf,
                                                    const short* __restrict__ B,
                                                    unsigned short* __restrict__ C,
                                                    int Mtiles, int Nclamp, int G,
                                                    const int* __restrict__ src,
                                                    const int* __restrict__ dst,
                                                    const int* __restrict__ cnt,
                                                    int* __restrict__ cursor,
                                                    int2* __restrict__ csr2, int E) {
    __shared__ __align__(16) short As[128 * 64];   // 16 KB
    __shared__ __align__(16) short Bs[256 * 64];   // 32 KB
    int b = blockIdx.x;
    if (b < G) {
        gemm_body<false, true>((const short*)nullptr, Xf, C, B, Mtiles, Nclamp, b, As, Bs);
    } else {
        int e = (b - G) * 256 + threadIdx.x;
        if (e >= E) return;
        int d = dst[e];
        int s = src[e];
        int rank = atomicAdd(&cursor[d], 1);
        int2 rec;
        rec.x = (s << 10) | ((s & 7) << 7);        // pre-rotated byte offset
        float dsv = rsqrtf((float)cnt[s] + 1.0f);
        float ddv = rsqrtf((float)cnt[d] + 1.0f);
        rec.y = __float_as_int(dsv * ddv);         // full symmetric norm
        csr2[(d << 6) + rank] = rec;
    }
}

// Layer-2 plain GEMM (A = h1, XOR-rotated bf16).
__global__ __launch_bounds__(256, 2) void gemm_bf16(const short* __restrict__ A,
                                                    const short* __restrict__ B,
                                                    unsigned short* __restrict__ C,
                                                    int Mtiles) {
    __shared__ __align__(16) short As[128 * 64];
    __shared__ __align__(16) short Bs[256 * 64];
    gemm_body<true, false>(A, (const float*)nullptr, C, B, Mtiles, 0, blockIdx.x, As, Bs);
}

// ---------------------------------------------------------------------------
// XCD-sharded aggregation: shard = blockIdx&7 covers 64 logical channels.
// XOR-rotated physical layout keeps the 3.2 MB/XCD gather set L2-resident.
// 8-record loads (R13): ONE VMEM instr covers TWO batch-4 rounds; off/wgt
// broadcast via __shfl from lanes base+half*4+t.
// ---------------------------------------------------------------------------
__device__ inline void cvt8(u16x8 v, float* f) {
#pragma unroll
    for (int j = 0; j < 8; ++j) f[j] = __uint_as_float((unsigned)v[j] << 16);
}

__global__ __launch_bounds__(256) void agg_relu_sh(const unsigned short* __restrict__ hw,
                                                   const int2* __restrict__ csr2,
                                                   const int* __restrict__ cnt,
                                                   const float* __restrict__ bias,
                                                   unsigned short* __restrict__ out,
                                                   const float* __restrict__ bo,
                                                   const float* __restrict__ bw,
                                                   float* __restrict__ outv,
                                                   int N, int Mpad) {
    int b = blockIdx.x;
    int shard = b & 7;
    int tid = threadIdx.x;
    int wave = tid >> 6, lane = tid & 63;
    int cluster = lane >> 3;
    int sub = lane & 7;
    int node = (b >> 3) * 32 + wave * 8 + cluster;
    int c0 = shard * 64 + sub * 8;                 // logical channel base
    int sgn = shard ^ (node & 7);                  // XOR-rotated physical group
    if (node >= N) {
        if (node < Mpad) {
            u16x8 z = {0, 0, 0, 0, 0, 0, 0, 0};
            *(u16x8*)&out[(size_t)node * HID + sgn * 64 + sub * 8] = z;
        }
        return;
    }

    if (shard == 0 && sub == 0) {                  // bias init (pre-agg_heads)
        outv[node] = bo[0];
        outv[N + node] = bw[0];
    }

    const char* hwb = (const char*)hw + sub * 16;  // sub part; group baked in record
    const int shardbyte = shard << 7;              // loop-invariant XOR key
    const int base = lane & 56;                    // cluster lane base for shfl
    int cdeg = cnt[node];
    float dn = rsqrtf((float)cdeg + 1.0f);
    int e0 = node << 6, e1 = e0 + cdeg;

    float acc[8];
    {
        u16x8 sv = *(const u16x8*)(hwb + ((size_t)node << 10) + sgn * 128);
        float g[8];
        cvt8(sv, g);
        float4 bb0 = *(const float4*)&bias[c0];
        float4 bb1 = *(const float4*)&bias[c0 + 4];
        float dis2 = dn * dn;
        acc[0] = g[0] * dis2 + bb0.x; acc[1] = g[1] * dis2 + bb0.y;
        acc[2] = g[2] * dis2 + bb0.z; acc[3] = g[3] * dis2 + bb0.w;
        acc[4] = g[4] * dis2 + bb1.x; acc[5] = g[5] * dis2 + bb1.y;
        acc[6] = g[6] * dis2 + bb1.z; acc[7] = g[7] * dis2 + bb1.w;
    }

    for (int e = e0; e < e1; e += 8) {
        // ONE record-load instr: lane (cluster, sub) fetches record e+sub
        int ee = e + sub;
        int ec = (ee < e1) ? ee : (e1 - 1);
        int2 rec = csr2[ec];
        int myoff = rec.x ^ shardbyte;
#pragma unroll
        for (int half = 0; half < 2; ++half) {
            int eh = e + half * 4;
            if (eh < e1) {
                int off[4]; float wgt[4];
#pragma unroll
                for (int t = 0; t < 4; ++t) {
                    off[t] = __shfl(myoff, base + half * 4 + t);
                    int wy = __shfl(rec.y, base + half * 4 + t);
                    wgt[t] = ((eh + t) < e1) ? __int_as_float(wy) : 0.f;
                }
                u16x8 v[4];
#pragma unroll
                for (int t = 0; t < 4; ++t)
                    v[t] = *(const u16x8*)(hwb + off[t]);
#pragma unroll
                for (int t = 0; t < 4; ++t) {
                    float g[8];
                    cvt8(v[t], g);
#pragma unroll
                    for (int u = 0; u < 8; ++u) acc[u] += g[u] * wgt[t];
                }
            }
        }
    }

    unsigned short o[8];
#pragma unroll
    for (int t = 0; t < 8; ++t) {
        __hip_bfloat16 v = __float2bfloat16(fmaxf(acc[t], 0.f));
        o[t] = *(unsigned short*)&v;
    }
    *(u16x8*)&out[(size_t)node * HID + sgn * 64 + sub * 8] = *(u16x8*)o;
}

// Layer-2 sharded aggregation + fused heads.
__global__ __launch_bounds__(256) void agg_heads_sh(const unsigned short* __restrict__ hw,
                                                    const int2* __restrict__ csr2,
                                                    const int* __restrict__ cnt,
                                                    const float* __restrict__ bias,
                                                    const float* __restrict__ Wo,
                                                    const float* __restrict__ Ww,
                                                    float* __restrict__ out, int N) {
    int b = blockIdx.x;
    int shard = b & 7;
    int tid = threadIdx.x;
    int wave = tid >> 6, lane = tid & 63;
    int cluster = lane >> 3;
    int sub = lane & 7;
    int node = (b >> 3) * 32 + wave * 8 + cluster;
    if (node >= N) return;
    int c0 = shard * 64 + sub * 8;
    int sgn = shard ^ (node & 7);

    const char* hwb = (const char*)hw + sub * 16;
    const int shardbyte = shard << 7;
    const int base = lane & 56;
    int cdeg = cnt[node];
    float dn = rsqrtf((float)cdeg + 1.0f);
    int e0 = node << 6, e1 = e0 + cdeg;

    float acc[8];
    {
        u16x8 sv = *(const u16x8*)(hwb + ((size_t)node << 10) + sgn * 128);
        float g[8];
        cvt8(sv, g);
        float4 bb0 = *(const float4*)&bias[c0];
        float4 bb1 = *(const float4*)&bias[c0 + 4];
        float dis2 = dn * dn;
        acc[0] = g[0] * dis2 + bb0.x; acc[1] = g[1] * dis2 + bb0.y;
        acc[2] = g[2] * dis2 + bb0.z; acc[3] = g[3] * dis2 + bb0.w;
        acc[4] = g[4] * dis2 + bb1.x; acc[5] = g[5] * dis2 + bb1.y;
        acc[6] = g[6] * dis2 + bb1.z; acc[7] = g[7] * dis2 + bb1.w;
    }

    for (int e = e0; e < e1; e += 8) {
        int ee = e + sub;
        int ec = (ee < e1) ? ee : (e1 - 1);
        int2 rec = csr2[ec];
        int myoff = rec.x ^ shardbyte;
#pragma unroll
        for (int half = 0; half < 2; ++half) {
            int eh = e + half * 4;
            if (eh < e1) {
                int off[4]; float wgt[4];
#pragma unroll
                for (int t = 0; t < 4; ++t) {
                    off[t] = __shfl(myoff, base + half * 4 + t);
                    int wy = __shfl(rec.y, base + half * 4 + t);
                    wgt[t] = ((eh + t) < e1) ? __int_as_float(wy) : 0.f;
                }
                u16x8 v[4];
#pragma unroll
                for (int t = 0; t < 4; ++t)
                    v[t] = *(const u16x8*)(hwb + off[t]);
#pragma unroll
                for (int t = 0; t < 4; ++t) {
                    float g[8];
                    cvt8(v[t], g);
#pragma unroll
                    for (int u = 0; u < 8; ++u) acc[u] += g[u] * wgt[t];
                }
            }
        }
    }

    float4 wo0 = *(const float4*)&Wo[c0];
    float4 wo1 = *(const float4*)&Wo[c0 + 4];
    float4 ww0 = *(const float4*)&Ww[c0];
    float4 ww1 = *(const float4*)&Ww[c0 + 4];
    float po = 0.f, pw = 0.f, h;
    h = fmaxf(acc[0], 0.f); po += h * wo0.x; pw += h * ww0.x;
    h = fmaxf(acc[1], 0.f); po += h * wo0.y; pw += h * ww0.y;
    h = fmaxf(acc[2], 0.f); po += h * wo0.z; pw += h * ww0.z;
    h = fmaxf(acc[3], 0.f); po += h * wo0.w; pw += h * ww0.w;
    h = fmaxf(acc[4], 0.f); po += h * wo1.x; pw += h * ww1.x;
    h = fmaxf(acc[5], 0.f); po += h * wo1.y; pw += h * ww1.y;
    h = fmaxf(acc[6], 0.f); po += h * wo1.z; pw += h * ww1.z;
    h = fmaxf(acc[7], 0.f); po += h * wo1.w; pw += h * ww1.w;

#pragma unroll
    for (int off2 = 4; off2 > 0; off2 >>= 1) {
        po += __shfl_down(po, off2);
        pw += __shfl_down(pw, off2);
    }
    if (sub == 0) {
        atomicAdd(&out[node], po);
        atomicAdd(&out[N + node], pw);
    }
}

// ---------------------------------------------------------------------------
extern "C" void kernel_launch(void* const* d_in, const int* in_sizes, int n_in,
                              void* d_out, int out_size, void* d_ws, size_t ws_size,
                              hipStream_t stream) {
    const float* x  = (const float*)d_in[0];
    const int*   ei = (const int*)d_in[1];
    const float* W1 = (const float*)d_in[2];
    const float* b1 = (const float*)d_in[3];
    const float* W2 = (const float*)d_in[4];
    const float* b2 = (const float*)d_in[5];
    const float* Wo = (const float*)d_in[6];
    const float* bo = (const float*)d_in[7];
    const float* Ww = (const float*)d_in[8];
    const float* bw = (const float*)d_in[9];

    const int N = in_sizes[0] / DIN;           // 25000
    const int E = in_sizes[1] / 2;             // 200000
    const int Mpad = (N + 127) & ~127;         // 25088
    const int Mtiles = Mpad / 128;             // 196
    const int EJ = (E + 255) / 256;            // edge blocks

    char* ws = (char*)d_ws;
    size_t p = 0;
    auto alloc = [&](size_t bytes) -> char* {
        char* r = ws + p;
        p += (bytes + 255) & ~(size_t)255;
        return r;
    };
    int*   cnt    = (int*)alloc((size_t)N * 2 * 4);        // cnt | cursor
    int*   cursor = cnt + N;
    int2*  csr2   = (int2*)alloc(((size_t)N << 6) * 8 + 64);  // fixed-stride CSR
    unsigned short* Wt1 = (unsigned short*)alloc((size_t)512 * 512 * 2);
    unsigned short* Wt2 = (unsigned short*)alloc((size_t)512 * 512 * 2);
    unsigned short* hw  = (unsigned short*)alloc((size_t)Mpad * 512 * 2);
    unsigned short* h1  = (unsigned short*)alloc((size_t)Mpad * 512 * 2);

    const int* src = ei;
    const int* dst = ei + E;

    hipMemsetAsync(cnt, 0, (size_t)N * 2 * 4, stream);

    prelude<<<512 + EJ, 256, 0, stream>>>(W1, W2, Wt1, Wt2, dst, cnt, E);

    const int G = 8 * ((Mtiles + 7) / 8) * 2;       // 400 gemm blocks
    // layer-1 GEMM (A staged from f32 x) with the CSR fill in the same launch
    gemm_fill<<<G + EJ, 256, 0, stream>>>(x, (const short*)Wt1, hw,
                                          Mtiles, N, G, src, dst, cnt, cursor, csr2, E);
    agg_relu_sh<<<8 * (Mpad / 32), 256, 0, stream>>>(hw, csr2, cnt, b1, h1,
                                                     bo, bw, (float*)d_out, N, Mpad);
    gemm_bf16<<<G, 256, 0, stream>>>((const short*)h1, (const short*)Wt2, hw, Mtiles);
    agg_heads_sh<<<8 * ((N + 31) / 32), 256, 0, stream>>>(hw, csr2, cnt, b2,
                                                          Wo, Ww, (float*)d_out, N);
}